// Round 8
// baseline (406.582 us; speedup 1.0000x reference)
//
#include <hip/hip_runtime.h>
#include <math.h>

#define B_ 4
#define C_ 64
#define M_ 8
#define H_ 224
#define W_ 224
#define N_ (H_*W_)        // 50176
#define NP_ 50240         // N_ + 64: padded channel stride for WORKSPACE arrays
                          // (N_*4 = 49*4096 exactly -> 4KiB-aligned channel rows
                          //  alias HBM channels; +64 floats breaks it)
#define CN_ (C_*N_)
#define CNP_ (C_*NP_)
#define MNP_ (M_*NP_)

__device__ __forceinline__ float relu6f(float v){ return fminf(fmaxf(v,0.0f),6.0f); }
__device__ __forceinline__ float softplusf(float v){
  return v > 0.0f ? v + log1pf(expf(-v)) : log1pf(expf(v));
}

#define FMA4(A, W, X) { A.x = fmaf((W), (X).x, A.x); A.y = fmaf((W), (X).y, A.y); \
                        A.z = fmaf((W), (X).z, A.z); A.w = fmaf((W), (X).w, A.w); }

// ---------------------------------------------------------------------------
// K1: h = relu6(bn(conv1x1(x))), K = softplus(conv1x1(x)+kb), Ksum[b][m] (atomic)
// LDS slab pipeline (round-7 structure). h/K written with padded stride NP_.
// ---------------------------------------------------------------------------
__global__ __launch_bounds__(256) void k_fc1k(const float* __restrict__ x,
                                              const float* __restrict__ w,
                                              const float* __restrict__ bn,
                                              const float* __restrict__ kw,
                                              const float* __restrict__ kb,
                                              float* __restrict__ h,
                                              float* __restrict__ Kq,
                                              float* __restrict__ Ksum)
{
  __shared__ float xsl[2*1024];   // [buf][c'(8)][px(128)]
  __shared__ float wl [2*512];    // [buf][c'(8)][oc(64)]
  __shared__ float kt [512];      // [c(64)][m(8)]
  const int tid  = threadIdx.x;
  const int b    = blockIdx.x / 392;
  const int pg   = blockIdx.x % 392;
  const int pix0 = pg*128;
  const float* xb = x + (size_t)b*CN_ + pix0;

  for (int idx = tid; idx < 512; idx += 256) {
    const int c = idx >> 3, m = idx & 7;
    kt[idx] = kw[m*64 + c];
  }
  const int scp = tid >> 5;            // c' 0..7
  const int spx = (tid & 31) << 2;     // px 0..124
  const int e0 = tid*2, e1 = tid*2+1;
  const int wc0 = e0 >> 6, wo0 = e0 & 63;
  const int wc1 = e1 >> 6, wo1 = e1 & 63;

  {
    const float4 xr = *(const float4*)(xb + (size_t)scp*N_ + spx);
    const float w0r = w[wo0*64 + wc0];
    const float w1r = w[wo1*64 + wc1];
    *(float4*)&xsl[scp*128 + spx] = xr;
    wl[e0] = w0r; wl[e1] = w1r;
  }
  __syncthreads();

  const int lane = tid & 63, wv_ = tid >> 6;
  const int och  = 2*wv_ + (lane >> 5);   // 0..7
  const int ocb  = och*8;
  const int px4  = (lane & 31) << 2;

  float4 ah[8];
  float4 ak = {0,0,0,0};
  #pragma unroll
  for (int i = 0; i < 8; ++i) ah[i] = make_float4(0.f,0.f,0.f,0.f);

  for (int ck = 0; ck < 8; ++ck) {
    const int cur = ck & 1, nxt = cur ^ 1;
    const float* xc = &xsl[cur*1024];
    const float* wc = &wl[cur*512];
    float4 xr; float w0r, w1r;
    if (ck < 7) {
      const int c0n = (ck+1)*8;
      xr  = *(const float4*)(xb + (size_t)(c0n + scp)*N_ + spx);
      w0r = w[wo0*64 + c0n + wc0];
      w1r = w[wo1*64 + c0n + wc1];
    }
    #pragma unroll
    for (int cp = 0; cp < 8; ++cp) {
      const float4 xv = *(const float4*)&xc[cp*128 + px4];
      const float4 w0 = *(const float4*)&wc[cp*64 + ocb];
      const float4 w1 = *(const float4*)&wc[cp*64 + ocb + 4];
      const float kvw = kt[(ck*8+cp)*8 + och];
      FMA4(ah[0], w0.x, xv); FMA4(ah[1], w0.y, xv);
      FMA4(ah[2], w0.z, xv); FMA4(ah[3], w0.w, xv);
      FMA4(ah[4], w1.x, xv); FMA4(ah[5], w1.y, xv);
      FMA4(ah[6], w1.z, xv); FMA4(ah[7], w1.w, xv);
      FMA4(ak, kvw, xv);
    }
    if (ck < 7) {
      *(float4*)&xsl[nxt*1024 + scp*128 + spx] = xr;
      wl[nxt*512 + e0] = w0r; wl[nxt*512 + e1] = w1r;
    }
    __syncthreads();
  }

  float* hb = h + (size_t)b*CNP_ + pix0 + px4;
  #pragma unroll
  for (int o = 0; o < 8; ++o) {
    const int oc = ocb + o;
    const float inv  = bn[oc] / sqrtf(bn[192+oc] + 1e-5f);
    const float beta = bn[64+oc] - bn[128+oc]*inv;
    float4 o4;
    o4.x = relu6f(fmaf(ah[o].x, inv, beta));
    o4.y = relu6f(fmaf(ah[o].y, inv, beta));
    o4.z = relu6f(fmaf(ah[o].z, inv, beta));
    o4.w = relu6f(fmaf(ah[o].w, inv, beta));
    *(float4*)(hb + (size_t)oc*NP_) = o4;
  }
  { // K row (m = och) + block-partial Ksum
    const float kbm = kb[och];
    float4 q;
    q.x = softplusf(ak.x + kbm); q.y = softplusf(ak.y + kbm);
    q.z = softplusf(ak.z + kbm); q.w = softplusf(ak.w + kbm);
    *(float4*)(Kq + ((size_t)b*M_ + och)*NP_ + pix0 + px4) = q;
    float part = q.x + q.y + q.z + q.w;
    part += __shfl_xor(part, 1);
    part += __shfl_xor(part, 2);
    part += __shfl_xor(part, 4);
    part += __shfl_xor(part, 8);
    part += __shfl_xor(part, 16);
    if ((lane & 31) == 0) atomicAdd(&Ksum[b*8 + och], part);
  }
}

// ---------------------------------------------------------------------------
// K2: s = relu6(bn1(dw5x5(h))) + relu6(bn2(dw3x3(h)))  — NP_-strided h,s
// ---------------------------------------------------------------------------
__global__ __launch_bounds__(256) void k_dw(const float* __restrict__ h,
                                            const float* __restrict__ w5,
                                            const float* __restrict__ w3,
                                            const float* __restrict__ bn1,
                                            const float* __restrict__ bn2,
                                            float* __restrict__ s)
{
  __shared__ float tile[36*37];
  const int tid = threadIdx.x;
  const int blk = blockIdx.x;              // B*C*49
  const int t   = blk % 49;
  const int bc  = blk / 49;
  const int c   = bc & 63;
  const int tx0 = (t % 7) * 32;
  const int ty0 = (t / 7) * 32;
  const float* hb = h + (size_t)bc * NP_;

  for (int idx = tid; idx < 1296; idx += 256) {
    const int ly = idx / 36, lx = idx - ly*36;
    const int gy = ty0 + ly - 2, gx = tx0 + lx - 2;
    float v = 0.0f;
    if (gy >= 0 && gy < H_ && gx >= 0 && gx < W_) v = hb[gy*W_ + gx];
    tile[ly*37 + lx] = v;
  }
  __syncthreads();

  float w5r[25], w3r[9];
  #pragma unroll
  for (int i = 0; i < 25; ++i) w5r[i] = w5[c*25 + i];
  #pragma unroll
  for (int i = 0; i < 9; ++i)  w3r[i] = w3[c*9 + i];
  const float inv1 = bn1[c] / sqrtf(bn1[192+c] + 1e-5f);
  const float bet1 = bn1[64+c] - bn1[128+c]*inv1;
  const float inv2 = bn2[c] / sqrtf(bn2[192+c] + 1e-5f);
  const float bet2 = bn2[64+c] - bn2[128+c]*inv2;

  const int ty  = tid >> 3;
  const int tx4 = (tid & 7) << 2;
  float a5[4] = {0,0,0,0}, a3[4] = {0,0,0,0};
  #pragma unroll
  for (int dy = 0; dy < 5; ++dy) {
    float r[8];
    #pragma unroll
    for (int i = 0; i < 8; ++i) r[i] = tile[(ty+dy)*37 + tx4 + i];
    #pragma unroll
    for (int dx = 0; dx < 5; ++dx) {
      const float wv = w5r[dy*5+dx];
      #pragma unroll
      for (int p = 0; p < 4; ++p) a5[p] = fmaf(wv, r[p+dx], a5[p]);
    }
    if (dy >= 1 && dy <= 3) {
      #pragma unroll
      for (int dx = 1; dx <= 3; ++dx) {
        const float wv = w3r[(dy-1)*3+(dx-1)];
        #pragma unroll
        for (int p = 0; p < 4; ++p) a3[p] = fmaf(wv, r[p+dx], a3[p]);
      }
    }
  }
  float* sb = s + (size_t)bc * NP_ + (ty0+ty)*W_ + tx0 + tx4;
  float4 o4;
  o4.x = relu6f(fmaf(a5[0],inv1,bet1)) + relu6f(fmaf(a3[0],inv2,bet2));
  o4.y = relu6f(fmaf(a5[1],inv1,bet1)) + relu6f(fmaf(a3[1],inv2,bet2));
  o4.z = relu6f(fmaf(a5[2],inv1,bet1)) + relu6f(fmaf(a3[2],inv2,bet2));
  o4.w = relu6f(fmaf(a5[3],inv1,bet1)) + relu6f(fmaf(a3[3],inv2,bet2));
  *(float4*)sb = o4;
}

// ---------------------------------------------------------------------------
// K3: FUSED V + KV.  V = conv1x1(x)+vb + relu6(bn(conv1x1(s))) stays in
// registers; per-block KV[m][c] partial via LDS tiles + atomicAdd.
// V never touches HBM (saves 102 MB vs round-7's k_v + k_kv).
// ---------------------------------------------------------------------------
__global__ __launch_bounds__(256) void k_vkv(const float* __restrict__ x,
                                             const float* __restrict__ s,
                                             const float* __restrict__ vw,
                                             const float* __restrict__ vb,
                                             const float* __restrict__ fw,
                                             const float* __restrict__ fbn,
                                             const float* __restrict__ Kq,
                                             float* __restrict__ KV)
{
  __shared__ float xsl[2*1024];
  __shared__ float ssl[2*1024];
  __shared__ float wvl[2*512];
  __shared__ float wfl[2*512];
  __shared__ float kts[8*128];     // K tile [m][px]
  __shared__ float vts[128*33];    // V half-tile [px][c'] (stride 33: bank-clean)
  const int tid  = threadIdx.x;
  const int b    = blockIdx.x / 392;
  const int pg   = blockIdx.x % 392;
  const int pix0 = pg*128;
  const float* xb = x + (size_t)b*CN_  + pix0;
  const float* sb = s + (size_t)b*CNP_ + pix0;

  { // K tile load (padded stride)
    const float* Kb = Kq + (size_t)b*MNP_ + pix0;
    for (int idx = tid; idx < 1024; idx += 256)
      kts[idx] = Kb[(size_t)(idx>>7)*NP_ + (idx&127)];
  }

  const int scp = tid >> 5;
  const int spx = (tid & 31) << 2;
  const int e0 = tid*2, e1 = tid*2+1;
  const int wc0 = e0 >> 6, wo0 = e0 & 63;
  const int wc1 = e1 >> 6, wo1 = e1 & 63;

  {
    const float4 xr = *(const float4*)(xb + (size_t)scp*N_  + spx);
    const float4 sr = *(const float4*)(sb + (size_t)scp*NP_ + spx);
    const float a0 = vw[wo0*64 + wc0], a1 = vw[wo1*64 + wc1];
    const float f0 = fw[wo0*64 + wc0], f1 = fw[wo1*64 + wc1];
    *(float4*)&xsl[scp*128 + spx] = xr;
    *(float4*)&ssl[scp*128 + spx] = sr;
    wvl[e0] = a0; wvl[e1] = a1;
    wfl[e0] = f0; wfl[e1] = f1;
  }
  __syncthreads();

  const int lane = tid & 63, wv_ = tid >> 6;
  const int och  = 2*wv_ + (lane >> 5);
  const int ocb  = och*8;
  const int px4  = (lane & 31) << 2;

  float4 av[8], af[8];
  #pragma unroll
  for (int i = 0; i < 8; ++i) { av[i] = make_float4(0,0,0,0); af[i] = make_float4(0,0,0,0); }

  for (int ck = 0; ck < 8; ++ck) {
    const int cur = ck & 1, nxt = cur ^ 1;
    const float* xc  = &xsl[cur*1024];
    const float* sc2 = &ssl[cur*1024];
    const float* wvc = &wvl[cur*512];
    const float* wfc = &wfl[cur*512];
    float4 xr, sr; float a0r, a1r, f0r, f1r;
    if (ck < 7) {
      const int c0n = (ck+1)*8;
      xr  = *(const float4*)(xb + (size_t)(c0n + scp)*N_  + spx);
      sr  = *(const float4*)(sb + (size_t)(c0n + scp)*NP_ + spx);
      a0r = vw[wo0*64 + c0n + wc0]; a1r = vw[wo1*64 + c0n + wc1];
      f0r = fw[wo0*64 + c0n + wc0]; f1r = fw[wo1*64 + c0n + wc1];
    }
    #pragma unroll
    for (int cp = 0; cp < 8; ++cp) {
      const float4 xv = *(const float4*)&xc[cp*128 + px4];
      const float4 sv = *(const float4*)&sc2[cp*128 + px4];
      const float4 wa0 = *(const float4*)&wvc[cp*64 + ocb];
      const float4 wa1 = *(const float4*)&wvc[cp*64 + ocb + 4];
      const float4 wf0 = *(const float4*)&wfc[cp*64 + ocb];
      const float4 wf1 = *(const float4*)&wfc[cp*64 + ocb + 4];
      FMA4(av[0], wa0.x, xv); FMA4(av[1], wa0.y, xv);
      FMA4(av[2], wa0.z, xv); FMA4(av[3], wa0.w, xv);
      FMA4(av[4], wa1.x, xv); FMA4(av[5], wa1.y, xv);
      FMA4(av[6], wa1.z, xv); FMA4(av[7], wa1.w, xv);
      FMA4(af[0], wf0.x, sv); FMA4(af[1], wf0.y, sv);
      FMA4(af[2], wf0.z, sv); FMA4(af[3], wf0.w, sv);
      FMA4(af[4], wf1.x, sv); FMA4(af[5], wf1.y, sv);
      FMA4(af[6], wf1.z, sv); FMA4(af[7], wf1.w, sv);
    }
    if (ck < 7) {
      *(float4*)&xsl[nxt*1024 + scp*128 + spx] = xr;
      *(float4*)&ssl[nxt*1024 + scp*128 + spx] = sr;
      wvl[nxt*512 + e0] = a0r; wvl[nxt*512 + e1] = a1r;
      wfl[nxt*512 + e0] = f0r; wfl[nxt*512 + e1] = f1r;
    }
    __syncthreads();
  }

  // finalize V into registers (epilogue math)
  float4 vf[8];
  #pragma unroll
  for (int o = 0; o < 8; ++o) {
    const int oc = ocb + o;
    const float inv  = fbn[oc] / sqrtf(fbn[192+oc] + 1e-5f);
    const float beta = fbn[64+oc] - fbn[128+oc]*inv;
    const float bias = vb[oc];
    vf[o].x = av[o].x + bias + relu6f(fmaf(af[o].x, inv, beta));
    vf[o].y = av[o].y + bias + relu6f(fmaf(af[o].y, inv, beta));
    vf[o].z = av[o].z + bias + relu6f(fmaf(af[o].z, inv, beta));
    vf[o].w = av[o].w + bias + relu6f(fmaf(af[o].w, inv, beta));
  }

  // two half-phases: c 0..31 then 32..63
  #pragma unroll
  for (int ph = 0; ph < 2; ++ph) {
    if ((och >> 2) == ph) {        // waves holding this c-half write vts
      const int rb = ocb - ph*32;
      #pragma unroll
      for (int o = 0; o < 8; ++o) {
        vts[(px4+0)*33 + rb+o] = vf[o].x;
        vts[(px4+1)*33 + rb+o] = vf[o].y;
        vts[(px4+2)*33 + rb+o] = vf[o].z;
        vts[(px4+3)*33 + rb+o] = vf[o].w;
      }
    }
    __syncthreads();
    {
      const int m = tid >> 5, cA = tid & 31;
      float acc = 0.0f;
      #pragma unroll 4
      for (int px = 0; px < 128; ++px)
        acc = fmaf(kts[m*128 + px], vts[px*33 + cA], acc);
      atomicAdd(&KV[b*512 + m*64 + ph*32 + cA], acc);
    }
    __syncthreads();
  }
}

// ---------------------------------------------------------------------------
// K5: out = x + gamma*(Q^T KV)/(Q^T(Ksum+eps)).  Thread = pixel, two register
// passes over c (no 64-KB LDS tile, no hot-path barrier; 2nd x pass is L2/L3).
// ---------------------------------------------------------------------------
__global__ __launch_bounds__(256) void k_out(const float* __restrict__ x,
                                             const float* __restrict__ qw,
                                             const float* __restrict__ qb,
                                             const float* __restrict__ gamma,
                                             const float* __restrict__ KV,
                                             const float* __restrict__ Ksum,
                                             float* __restrict__ out)
{
  __shared__ __align__(16) float kvt[64*8];    // [c][m]
  __shared__ __align__(16) float wqt[64*8];    // [c][m]
  __shared__ float ksl[8];
  const int tid = threadIdx.x;
  const int b  = blockIdx.x / 196;
  const int pg = blockIdx.x % 196;
  const int px = pg*256 + tid;
  for (int idx = tid; idx < 512; idx += 256) {
    const int m = idx >> 6, c = idx & 63;
    kvt[c*8 + m] = KV[b*512 + idx];
    wqt[c*8 + m] = qw[idx];
  }
  if (tid < 8) ksl[tid] = Ksum[b*8 + tid] + 1e-6f;
  __syncthreads();

  const float* xb = x + (size_t)b*CN_ + px;
  float q0=0,q1=0,q2=0,q3=0,q4=0,q5=0,q6=0,q7=0;

#define QSTEP(XV, CC) { \
    const float4 wA = *(const float4*)&wqt[(CC)*8]; \
    const float4 wB = *(const float4*)&wqt[(CC)*8+4]; \
    q0=fmaf(wA.x,(XV),q0); q1=fmaf(wA.y,(XV),q1); \
    q2=fmaf(wA.z,(XV),q2); q3=fmaf(wA.w,(XV),q3); \
    q4=fmaf(wB.x,(XV),q4); q5=fmaf(wB.y,(XV),q5); \
    q6=fmaf(wB.z,(XV),q6); q7=fmaf(wB.w,(XV),q7); }

  #pragma unroll
  for (int g = 0; g < 8; ++g) {
    const int c0 = g*8;
    const float x0 = xb[(size_t)(c0+0)*N_];
    const float x1 = xb[(size_t)(c0+1)*N_];
    const float x2 = xb[(size_t)(c0+2)*N_];
    const float x3 = xb[(size_t)(c0+3)*N_];
    const float x4 = xb[(size_t)(c0+4)*N_];
    const float x5 = xb[(size_t)(c0+5)*N_];
    const float x6 = xb[(size_t)(c0+6)*N_];
    const float x7 = xb[(size_t)(c0+7)*N_];
    QSTEP(x0,c0+0); QSTEP(x1,c0+1); QSTEP(x2,c0+2); QSTEP(x3,c0+3);
    QSTEP(x4,c0+4); QSTEP(x5,c0+5); QSTEP(x6,c0+6); QSTEP(x7,c0+7);
  }
#undef QSTEP

  q0 = softplusf(q0 + qb[0]); q1 = softplusf(q1 + qb[1]);
  q2 = softplusf(q2 + qb[2]); q3 = softplusf(q3 + qb[3]);
  q4 = softplusf(q4 + qb[4]); q5 = softplusf(q5 + qb[5]);
  q6 = softplusf(q6 + qb[6]); q7 = softplusf(q7 + qb[7]);
  float den = q0*ksl[0];
  den = fmaf(q1, ksl[1], den); den = fmaf(q2, ksl[2], den);
  den = fmaf(q3, ksl[3], den); den = fmaf(q4, ksl[4], den);
  den = fmaf(q5, ksl[5], den); den = fmaf(q6, ksl[6], den);
  den = fmaf(q7, ksl[7], den);
  const float sc = gamma[0] / den;

  float* ob = out + (size_t)b*CN_ + px;
#define OSTEP(XV, CC) { \
    const float4 kA = *(const float4*)&kvt[(CC)*8]; \
    const float4 kB = *(const float4*)&kvt[(CC)*8+4]; \
    float wv = q0*kA.x; wv=fmaf(q1,kA.y,wv); wv=fmaf(q2,kA.z,wv); wv=fmaf(q3,kA.w,wv); \
    wv=fmaf(q4,kB.x,wv); wv=fmaf(q5,kB.y,wv); wv=fmaf(q6,kB.z,wv); wv=fmaf(q7,kB.w,wv); \
    ob[(size_t)(CC)*N_] = fmaf(sc, wv, (XV)); }

  #pragma unroll
  for (int g = 0; g < 8; ++g) {
    const int c0 = g*8;
    const float x0 = xb[(size_t)(c0+0)*N_];
    const float x1 = xb[(size_t)(c0+1)*N_];
    const float x2 = xb[(size_t)(c0+2)*N_];
    const float x3 = xb[(size_t)(c0+3)*N_];
    const float x4 = xb[(size_t)(c0+4)*N_];
    const float x5 = xb[(size_t)(c0+5)*N_];
    const float x6 = xb[(size_t)(c0+6)*N_];
    const float x7 = xb[(size_t)(c0+7)*N_];
    OSTEP(x0,c0+0); OSTEP(x1,c0+1); OSTEP(x2,c0+2); OSTEP(x3,c0+3);
    OSTEP(x4,c0+4); OSTEP(x5,c0+5); OSTEP(x6,c0+6); OSTEP(x7,c0+7);
  }
#undef OSTEP
}

// ---------------------------------------------------------------------------
extern "C" void kernel_launch(void* const* d_in, const int* in_sizes, int n_in,
                              void* d_out, int out_size, void* d_ws, size_t ws_size,
                              hipStream_t stream) {
  const float* x      = (const float*)d_in[0];
  const float* gamma  = (const float*)d_in[1];
  const float* q_w    = (const float*)d_in[2];
  const float* q_b    = (const float*)d_in[3];
  const float* k_w    = (const float*)d_in[4];
  const float* k_b    = (const float*)d_in[5];
  const float* v_w    = (const float*)d_in[6];
  const float* v_b    = (const float*)d_in[7];
  const float* fc1_w  = (const float*)d_in[8];
  const float* fc1_bn = (const float*)d_in[9];
  const float* c1_w   = (const float*)d_in[10];
  const float* c1_bn  = (const float*)d_in[11];
  const float* c2_w   = (const float*)d_in[12];
  const float* c2_bn  = (const float*)d_in[13];
  const float* fc2_w  = (const float*)d_in[14];
  const float* fc2_bn = (const float*)d_in[15];
  float* outp = (float*)d_out;

  float* ws   = (float*)d_ws;
  float* bufH = ws;                                   // B*C*NP_
  float* bufS = bufH + (size_t)B_*CNP_;               // B*C*NP_
  float* bufK = bufS + (size_t)B_*CNP_;               // B*M*NP_
  float* kv   = bufK + (size_t)B_*MNP_;               // 2048
  float* ksum = kv + 2048;                            // 32

  hipMemsetAsync(kv, 0, (2048 + 32)*sizeof(float), stream);

  k_fc1k<<<dim3(B_*392), dim3(256), 0, stream>>>(x, fc1_w, fc1_bn, k_w, k_b,
                                                 bufH, bufK, ksum);
  k_dw  <<<dim3(B_*C_*49), dim3(256), 0, stream>>>(bufH, c1_w, c2_w, c1_bn, c2_bn, bufS);
  k_vkv <<<dim3(B_*392), dim3(256), 0, stream>>>(x, bufS, v_w, v_b, fc2_w, fc2_bn,
                                                 bufK, kv);
  k_out <<<dim3(B_*196), dim3(256), 0, stream>>>(x, q_w, q_b, gamma, kv, ksum, outp);
}

// Round 9
// 360.692 us; speedup vs baseline: 1.1272x; 1.1272x over previous
//
#include <hip/hip_runtime.h>
#include <math.h>

#define B_ 4
#define C_ 64
#define M_ 8
#define H_ 224
#define W_ 224
#define N_ (H_*W_)        // 50176
#define NP_ 50240         // padded workspace channel stride (breaks 4KiB alias)
#define CN_ (C_*N_)
#define CNP_ (C_*NP_)
#define MNP_ (M_*NP_)

__device__ __forceinline__ float relu6f(float v){ return fminf(fmaxf(v,0.0f),6.0f); }
__device__ __forceinline__ float softplusf(float v){
  return v > 0.0f ? v + log1pf(expf(-v)) : log1pf(expf(v));
}

#define FMA4(A, W, X) { A.x = fmaf((W), (X).x, A.x); A.y = fmaf((W), (X).y, A.y); \
                        A.z = fmaf((W), (X).z, A.z); A.w = fmaf((W), (X).w, A.w); }

// ---------------------------------------------------------------------------
// K1: h = relu6(bn(conv1x1(x))), K = softplus(conv1x1(x)+kb), Ksum (atomic)
// r8 version (LDS slab pipeline, padded outputs) — was below the 104 µs radar.
// ---------------------------------------------------------------------------
__global__ __launch_bounds__(256) void k_fc1k(const float* __restrict__ x,
                                              const float* __restrict__ w,
                                              const float* __restrict__ bn,
                                              const float* __restrict__ kw,
                                              const float* __restrict__ kb,
                                              float* __restrict__ h,
                                              float* __restrict__ Kq,
                                              float* __restrict__ Ksum)
{
  __shared__ float xsl[2*1024];
  __shared__ float wl [2*512];
  __shared__ float kt [512];
  const int tid  = threadIdx.x;
  const int b    = blockIdx.x / 392;
  const int pg   = blockIdx.x % 392;
  const int pix0 = pg*128;
  const float* xb = x + (size_t)b*CN_ + pix0;

  for (int idx = tid; idx < 512; idx += 256) {
    const int c = idx >> 3, m = idx & 7;
    kt[idx] = kw[m*64 + c];
  }
  const int scp = tid >> 5;
  const int spx = (tid & 31) << 2;
  const int e0 = tid*2, e1 = tid*2+1;
  const int wc0 = e0 >> 6, wo0 = e0 & 63;
  const int wc1 = e1 >> 6, wo1 = e1 & 63;

  {
    const float4 xr = *(const float4*)(xb + (size_t)scp*N_ + spx);
    const float w0r = w[wo0*64 + wc0];
    const float w1r = w[wo1*64 + wc1];
    *(float4*)&xsl[scp*128 + spx] = xr;
    wl[e0] = w0r; wl[e1] = w1r;
  }
  __syncthreads();

  const int lane = tid & 63, wv_ = tid >> 6;
  const int och  = 2*wv_ + (lane >> 5);
  const int ocb  = och*8;
  const int px4  = (lane & 31) << 2;

  float4 ah[8];
  float4 ak = {0,0,0,0};
  #pragma unroll
  for (int i = 0; i < 8; ++i) ah[i] = make_float4(0.f,0.f,0.f,0.f);

  for (int ck = 0; ck < 8; ++ck) {
    const int cur = ck & 1, nxt = cur ^ 1;
    const float* xc = &xsl[cur*1024];
    const float* wc = &wl[cur*512];
    float4 xr; float w0r, w1r;
    if (ck < 7) {
      const int c0n = (ck+1)*8;
      xr  = *(const float4*)(xb + (size_t)(c0n + scp)*N_ + spx);
      w0r = w[wo0*64 + c0n + wc0];
      w1r = w[wo1*64 + c0n + wc1];
    }
    #pragma unroll
    for (int cp = 0; cp < 8; ++cp) {
      const float4 xv = *(const float4*)&xc[cp*128 + px4];
      const float4 w0 = *(const float4*)&wc[cp*64 + ocb];
      const float4 w1 = *(const float4*)&wc[cp*64 + ocb + 4];
      const float kvw = kt[(ck*8+cp)*8 + och];
      FMA4(ah[0], w0.x, xv); FMA4(ah[1], w0.y, xv);
      FMA4(ah[2], w0.z, xv); FMA4(ah[3], w0.w, xv);
      FMA4(ah[4], w1.x, xv); FMA4(ah[5], w1.y, xv);
      FMA4(ah[6], w1.z, xv); FMA4(ah[7], w1.w, xv);
      FMA4(ak, kvw, xv);
    }
    if (ck < 7) {
      *(float4*)&xsl[nxt*1024 + scp*128 + spx] = xr;
      wl[nxt*512 + e0] = w0r; wl[nxt*512 + e1] = w1r;
    }
    __syncthreads();
  }

  float* hb = h + (size_t)b*CNP_ + pix0 + px4;
  #pragma unroll
  for (int o = 0; o < 8; ++o) {
    const int oc = ocb + o;
    const float inv  = bn[oc] / sqrtf(bn[192+oc] + 1e-5f);
    const float beta = bn[64+oc] - bn[128+oc]*inv;
    float4 o4;
    o4.x = relu6f(fmaf(ah[o].x, inv, beta));
    o4.y = relu6f(fmaf(ah[o].y, inv, beta));
    o4.z = relu6f(fmaf(ah[o].z, inv, beta));
    o4.w = relu6f(fmaf(ah[o].w, inv, beta));
    *(float4*)(hb + (size_t)oc*NP_) = o4;
  }
  {
    const float kbm = kb[och];
    float4 q;
    q.x = softplusf(ak.x + kbm); q.y = softplusf(ak.y + kbm);
    q.z = softplusf(ak.z + kbm); q.w = softplusf(ak.w + kbm);
    *(float4*)(Kq + ((size_t)b*M_ + och)*NP_ + pix0 + px4) = q;
    float part = q.x + q.y + q.z + q.w;
    part += __shfl_xor(part, 1);
    part += __shfl_xor(part, 2);
    part += __shfl_xor(part, 4);
    part += __shfl_xor(part, 8);
    part += __shfl_xor(part, 16);
    if ((lane & 31) == 0) atomicAdd(&Ksum[b*8 + och], part);
  }
}

// ---------------------------------------------------------------------------
// K2: s = relu6(bn1(dw5x5(h))) + relu6(bn2(dw3x3(h)))  — NP_ strides
// ---------------------------------------------------------------------------
__global__ __launch_bounds__(256) void k_dw(const float* __restrict__ h,
                                            const float* __restrict__ w5,
                                            const float* __restrict__ w3,
                                            const float* __restrict__ bn1,
                                            const float* __restrict__ bn2,
                                            float* __restrict__ s)
{
  __shared__ float tile[36*37];
  const int tid = threadIdx.x;
  const int blk = blockIdx.x;
  const int t   = blk % 49;
  const int bc  = blk / 49;
  const int c   = bc & 63;
  const int tx0 = (t % 7) * 32;
  const int ty0 = (t / 7) * 32;
  const float* hb = h + (size_t)bc * NP_;

  for (int idx = tid; idx < 1296; idx += 256) {
    const int ly = idx / 36, lx = idx - ly*36;
    const int gy = ty0 + ly - 2, gx = tx0 + lx - 2;
    float v = 0.0f;
    if (gy >= 0 && gy < H_ && gx >= 0 && gx < W_) v = hb[gy*W_ + gx];
    tile[ly*37 + lx] = v;
  }
  __syncthreads();

  float w5r[25], w3r[9];
  #pragma unroll
  for (int i = 0; i < 25; ++i) w5r[i] = w5[c*25 + i];
  #pragma unroll
  for (int i = 0; i < 9; ++i)  w3r[i] = w3[c*9 + i];
  const float inv1 = bn1[c] / sqrtf(bn1[192+c] + 1e-5f);
  const float bet1 = bn1[64+c] - bn1[128+c]*inv1;
  const float inv2 = bn2[c] / sqrtf(bn2[192+c] + 1e-5f);
  const float bet2 = bn2[64+c] - bn2[128+c]*inv2;

  const int ty  = tid >> 3;
  const int tx4 = (tid & 7) << 2;
  float a5[4] = {0,0,0,0}, a3[4] = {0,0,0,0};
  #pragma unroll
  for (int dy = 0; dy < 5; ++dy) {
    float r[8];
    #pragma unroll
    for (int i = 0; i < 8; ++i) r[i] = tile[(ty+dy)*37 + tx4 + i];
    #pragma unroll
    for (int dx = 0; dx < 5; ++dx) {
      const float wv = w5r[dy*5+dx];
      #pragma unroll
      for (int p = 0; p < 4; ++p) a5[p] = fmaf(wv, r[p+dx], a5[p]);
    }
    if (dy >= 1 && dy <= 3) {
      #pragma unroll
      for (int dx = 1; dx <= 3; ++dx) {
        const float wv = w3r[(dy-1)*3+(dx-1)];
        #pragma unroll
        for (int p = 0; p < 4; ++p) a3[p] = fmaf(wv, r[p+dx], a3[p]);
      }
    }
  }
  float* sb = s + (size_t)bc * NP_ + (ty0+ty)*W_ + tx0 + tx4;
  float4 o4;
  o4.x = relu6f(fmaf(a5[0],inv1,bet1)) + relu6f(fmaf(a3[0],inv2,bet2));
  o4.y = relu6f(fmaf(a5[1],inv1,bet1)) + relu6f(fmaf(a3[1],inv2,bet2));
  o4.z = relu6f(fmaf(a5[2],inv1,bet1)) + relu6f(fmaf(a3[2],inv2,bet2));
  o4.w = relu6f(fmaf(a5[3],inv1,bet1)) + relu6f(fmaf(a3[3],inv2,bet2));
  *(float4*)sb = o4;
}

// ---------------------------------------------------------------------------
// K3: V = conv1x1(x)+vb + relu6(bn(conv1x1(s))) — UNFUSED again (r8 fusion's
// 800K atomics regressed). EXPERIMENT: 512-thread (8-wave) blocks, 256-px
// tile — tests whether r7's 29% occupancy was a blocks-per-CU cap.
// wave = 8 oc (och=wave), thread = 4 px; same slab pipeline, VGPR ~64.
// ---------------------------------------------------------------------------
__global__ __launch_bounds__(512) void k_v(const float* __restrict__ x,
                                           const float* __restrict__ s,
                                           const float* __restrict__ vw,
                                           const float* __restrict__ vb,
                                           const float* __restrict__ fw,
                                           const float* __restrict__ fbn,
                                           float* __restrict__ V)
{
  __shared__ float xsl[2*2048];   // [buf][c'(8)][px(256)]
  __shared__ float ssl[2*2048];
  __shared__ float wvl[2*512];    // [buf][c'(8)][oc(64)]
  __shared__ float wfl[2*512];
  const int tid  = threadIdx.x;
  const int b    = blockIdx.x / 196;
  const int pg   = blockIdx.x % 196;
  const int pix0 = pg*256;
  const float* xb = x + (size_t)b*CN_  + pix0;
  const float* sb = s + (size_t)b*CNP_ + pix0;

  // staging roles: one float4 of x and s per thread, one weight per array
  const int scp = tid >> 6;            // c' 0..7
  const int spx = (tid & 63) << 2;     // px 0..252
  const int wc  = tid >> 6;            // weight c' 0..7
  const int wo  = tid & 63;            // weight oc 0..63

  {
    const float4 xr = *(const float4*)(xb + (size_t)scp*N_  + spx);
    const float4 sr = *(const float4*)(sb + (size_t)scp*NP_ + spx);
    const float a0 = vw[wo*64 + wc];
    const float f0 = fw[wo*64 + wc];
    *(float4*)&xsl[scp*256 + spx] = xr;
    *(float4*)&ssl[scp*256 + spx] = sr;
    wvl[tid] = a0; wfl[tid] = f0;
  }
  __syncthreads();

  const int och = tid >> 6;            // wave = oc-group 0..7
  const int ocb = och*8;
  const int px4 = (tid & 63) << 2;

  float4 av[8], af[8];
  #pragma unroll
  for (int i = 0; i < 8; ++i) { av[i] = make_float4(0,0,0,0); af[i] = make_float4(0,0,0,0); }

  for (int ck = 0; ck < 8; ++ck) {
    const int cur = ck & 1, nxt = cur ^ 1;
    const float* xc  = &xsl[cur*2048];
    const float* sc2 = &ssl[cur*2048];
    const float* wvc = &wvl[cur*512];
    const float* wfc = &wfl[cur*512];
    float4 xr, sr; float a0r, f0r;
    if (ck < 7) {
      const int c0n = (ck+1)*8;
      xr  = *(const float4*)(xb + (size_t)(c0n + scp)*N_  + spx);
      sr  = *(const float4*)(sb + (size_t)(c0n + scp)*NP_ + spx);
      a0r = vw[wo*64 + c0n + wc];
      f0r = fw[wo*64 + c0n + wc];
    }
    #pragma unroll
    for (int cp = 0; cp < 8; ++cp) {
      const float4 xv  = *(const float4*)&xc [cp*256 + px4];
      const float4 sv  = *(const float4*)&sc2[cp*256 + px4];
      const float4 wa0 = *(const float4*)&wvc[cp*64 + ocb];
      const float4 wa1 = *(const float4*)&wvc[cp*64 + ocb + 4];
      const float4 wf0 = *(const float4*)&wfc[cp*64 + ocb];
      const float4 wf1 = *(const float4*)&wfc[cp*64 + ocb + 4];
      FMA4(av[0], wa0.x, xv); FMA4(av[1], wa0.y, xv);
      FMA4(av[2], wa0.z, xv); FMA4(av[3], wa0.w, xv);
      FMA4(av[4], wa1.x, xv); FMA4(av[5], wa1.y, xv);
      FMA4(av[6], wa1.z, xv); FMA4(av[7], wa1.w, xv);
      FMA4(af[0], wf0.x, sv); FMA4(af[1], wf0.y, sv);
      FMA4(af[2], wf0.z, sv); FMA4(af[3], wf0.w, sv);
      FMA4(af[4], wf1.x, sv); FMA4(af[5], wf1.y, sv);
      FMA4(af[6], wf1.z, sv); FMA4(af[7], wf1.w, sv);
    }
    if (ck < 7) {
      *(float4*)&xsl[nxt*2048 + scp*256 + spx] = xr;
      *(float4*)&ssl[nxt*2048 + scp*256 + spx] = sr;
      wvl[nxt*512 + tid] = a0r;
      wfl[nxt*512 + tid] = f0r;
    }
    __syncthreads();
  }

  float* Vb = V + (size_t)b*CNP_ + pix0 + px4;
  #pragma unroll
  for (int o = 0; o < 8; ++o) {
    const int oc = ocb + o;
    const float inv  = fbn[oc] / sqrtf(fbn[192+oc] + 1e-5f);
    const float beta = fbn[64+oc] - fbn[128+oc]*inv;
    const float bias = vb[oc];
    float4 o4;
    o4.x = av[o].x + bias + relu6f(fmaf(af[o].x, inv, beta));
    o4.y = av[o].y + bias + relu6f(fmaf(af[o].y, inv, beta));
    o4.z = av[o].z + bias + relu6f(fmaf(af[o].z, inv, beta));
    o4.w = av[o].w + bias + relu6f(fmaf(af[o].w, inv, beta));
    *(float4*)(Vb + (size_t)oc*NP_) = o4;
  }
}

// ---------------------------------------------------------------------------
// K4: KV[b,m,c] = sum_n K[b,m,n]*V[b,c,n]  (Ksum moved into k_fc1k)
// ---------------------------------------------------------------------------
__global__ __launch_bounds__(256) void k_kv(const float* __restrict__ V,
                                            const float* __restrict__ Kq,
                                            float* __restrict__ KV)
{
  const int blk = blockIdx.x;
  const int b   = blk >> 7;
  const int rem = blk & 127;
  const int cg  = rem >> 4;
  const int ch  = rem & 15;
  const int tid = threadIdx.x;
  const int base = ch * 3136;
  const int end  = base + 3136;
  const float* Kb = Kq + (size_t)b*MNP_;
  const float* Vb = V  + (size_t)b*CNP_ + (size_t)(cg*8)*NP_;

  float acc[64];
  #pragma unroll
  for (int i = 0; i < 64; ++i) acc[i] = 0.0f;

  for (int n = base + tid; n < end; n += 256) {
    float kv[8];
    #pragma unroll
    for (int m2 = 0; m2 < 8; ++m2) kv[m2] = Kb[(size_t)m2*NP_ + n];
    #pragma unroll
    for (int c8 = 0; c8 < 8; ++c8) {
      const float vv = Vb[(size_t)c8*NP_ + n];
      #pragma unroll
      for (int m2 = 0; m2 < 8; ++m2)
        acc[m2*8+c8] = fmaf(kv[m2], vv, acc[m2*8+c8]);
    }
  }
  const int lane = tid & 63;
  float mine = 0.0f;
  #pragma unroll
  for (int jj = 0; jj < 64; ++jj) {
    float v = acc[jj];
    v += __shfl_xor(v, 1);
    v += __shfl_xor(v, 2);
    v += __shfl_xor(v, 4);
    v += __shfl_xor(v, 8);
    v += __shfl_xor(v, 16);
    v += __shfl_xor(v, 32);
    if (lane == jj) mine = v;
  }
  atomicAdd(&KV[b*512 + (lane>>3)*64 + cg*8 + (lane&7)], mine);
}

// ---------------------------------------------------------------------------
// K5: out = x + gamma*(Q^T KV)/(Q^T(Ksum+eps)) — r7 proven version
// (LDS x tile, VGPR 88; r8's register 2-pass hit VGPR 256 + spill).
// ---------------------------------------------------------------------------
__global__ __launch_bounds__(256) void k_out(const float* __restrict__ x,
                                             const float* __restrict__ qw,
                                             const float* __restrict__ qb,
                                             const float* __restrict__ gamma,
                                             const float* __restrict__ KV,
                                             const float* __restrict__ Ksum,
                                             float* __restrict__ out)
{
  __shared__ float xs[64*256];
  __shared__ __align__(16) float kvt[64*8];
  __shared__ __align__(16) float wqt[64*8];
  __shared__ float ksl[8];
  const int tid = threadIdx.x;
  const int b  = blockIdx.x / 196;
  const int pg = blockIdx.x % 196;
  const int pix0 = pg*256;
  const float* xb = x + (size_t)b*CN_ + pix0;

  for (int idx = tid; idx < 512; idx += 256) {
    const int m = idx >> 6, c = idx & 63;
    kvt[c*8 + m] = KV[b*512 + idx];
    wqt[c*8 + m] = qw[idx];
  }
  if (tid < 8) ksl[tid] = Ksum[b*8 + tid] + 1e-6f;
  for (int idx = tid; idx < 4096; idx += 256) {
    const int c = idx >> 6, i = idx & 63;
    const float4 v = ((const float4*)(xb + (size_t)c*N_))[i];
    ((float4*)&xs[c*256])[i] = v;
  }
  __syncthreads();

  float q[8] = {0,0,0,0,0,0,0,0};
  #pragma unroll 8
  for (int c = 0; c < 64; ++c) {
    const float xv = xs[c*256 + tid];
    const float4 w0 = *(const float4*)&wqt[c*8];
    const float4 w1 = *(const float4*)&wqt[c*8+4];
    q[0] = fmaf(w0.x, xv, q[0]);
    q[1] = fmaf(w0.y, xv, q[1]);
    q[2] = fmaf(w0.z, xv, q[2]);
    q[3] = fmaf(w0.w, xv, q[3]);
    q[4] = fmaf(w1.x, xv, q[4]);
    q[5] = fmaf(w1.y, xv, q[5]);
    q[6] = fmaf(w1.z, xv, q[6]);
    q[7] = fmaf(w1.w, xv, q[7]);
  }
  float den = 0.0f;
  #pragma unroll
  for (int m = 0; m < 8; ++m) {
    q[m] = softplusf(q[m] + qb[m]);
    den  = fmaf(q[m], ksl[m], den);
  }
  const float sc = gamma[0] / den;

  float* ob = out + (size_t)b*CN_ + pix0 + tid;
  #pragma unroll 8
  for (int c = 0; c < 64; ++c) {
    const float4 k0 = *(const float4*)&kvt[c*8];
    const float4 k1 = *(const float4*)&kvt[c*8+4];
    float wv;
    wv = q[0]*k0.x;
    wv = fmaf(q[1], k0.y, wv);
    wv = fmaf(q[2], k0.z, wv);
    wv = fmaf(q[3], k0.w, wv);
    wv = fmaf(q[4], k1.x, wv);
    wv = fmaf(q[5], k1.y, wv);
    wv = fmaf(q[6], k1.z, wv);
    wv = fmaf(q[7], k1.w, wv);
    ob[(size_t)c*N_] = fmaf(sc, wv, xs[c*256 + tid]);
  }
}

// ---------------------------------------------------------------------------
extern "C" void kernel_launch(void* const* d_in, const int* in_sizes, int n_in,
                              void* d_out, int out_size, void* d_ws, size_t ws_size,
                              hipStream_t stream) {
  const float* x      = (const float*)d_in[0];
  const float* gamma  = (const float*)d_in[1];
  const float* q_w    = (const float*)d_in[2];
  const float* q_b    = (const float*)d_in[3];
  const float* k_w    = (const float*)d_in[4];
  const float* k_b    = (const float*)d_in[5];
  const float* v_w    = (const float*)d_in[6];
  const float* v_b    = (const float*)d_in[7];
  const float* fc1_w  = (const float*)d_in[8];
  const float* fc1_bn = (const float*)d_in[9];
  const float* c1_w   = (const float*)d_in[10];
  const float* c1_bn  = (const float*)d_in[11];
  const float* c2_w   = (const float*)d_in[12];
  const float* c2_bn  = (const float*)d_in[13];
  const float* fc2_w  = (const float*)d_in[14];
  const float* fc2_bn = (const float*)d_in[15];
  float* outp = (float*)d_out;

  float* ws   = (float*)d_ws;
  float* bufH = ws;                                   // h, later reused for V
  float* bufS = bufH + (size_t)B_*CNP_;
  float* bufK = bufS + (size_t)B_*CNP_;
  float* kv   = bufK + (size_t)B_*MNP_;
  float* ksum = kv + 2048;

  hipMemsetAsync(kv, 0, (2048 + 32)*sizeof(float), stream);

  k_fc1k<<<dim3(B_*392), dim3(256), 0, stream>>>(x, fc1_w, fc1_bn, k_w, k_b,
                                                 bufH, bufK, ksum);
  k_dw  <<<dim3(B_*C_*49), dim3(256), 0, stream>>>(bufH, c1_w, c2_w, c1_bn, c2_bn, bufS);
  k_v   <<<dim3(B_*196), dim3(512), 0, stream>>>(x, bufS, v_w, v_b, fc2_w, fc2_bn, bufH);
  k_kv  <<<dim3(512), dim3(256), 0, stream>>>(bufH, bufK, kv);
  k_out <<<dim3(B_*196), dim3(256), 0, stream>>>(x, q_w, q_b, gamma, kv, ksum, outp);
}